// Round 1
// baseline (4049.569 us; speedup 1.0000x reference)
//
#include <hip/hip_runtime.h>
#include <stdint.h>

#define G_   250
#define P_   200
#define EPG  3200
#define E_   800000
#define F_   128
#define R_   8
#define HROW 136   // f16 elems per h row (pad 8)
#define SROW 132   // f32 elems per S row (pad 4)

typedef _Float16 f16x8 __attribute__((ext_vector_type(8)));
typedef _Float16 f16x4 __attribute__((ext_vector_type(4)));
typedef float    f32x4 __attribute__((ext_vector_type(4)));

// ---------------- prepass 1: bucket edges by relation within each graph ----------------
// edges are contiguous per graph (g's edges at [g*3200, (g+1)*3200)); src/dst local < 200.
// record: src | dst<<8 | f16(1/cnt[dst,rel])<<16
__global__ __launch_bounds__(256) void k_bucket(const int* __restrict__ ei, const int* __restrict__ et,
                                                uint32_t* __restrict__ ebuf, int* __restrict__ ecnt,
                                                int* __restrict__ eoff) {
  __shared__ int cnt[P_ * R_];
  __shared__ int relCnt[R_], relOff[R_], cur[R_];
  int g = blockIdx.x, tid = threadIdx.x;
  for (int i = tid; i < P_ * R_; i += 256) cnt[i] = 0;
  if (tid < R_) { relCnt[tid] = 0; cur[tid] = 0; }
  __syncthreads();
  int base = g * EPG, nbase = g * P_;
  for (int e = tid; e < EPG; e += 256) {
    int d = ei[E_ + base + e] - nbase;
    int r = et[base + e];
    atomicAdd(&cnt[d * R_ + r], 1);
    atomicAdd(&relCnt[r], 1);
  }
  __syncthreads();
  if (tid == 0) {
    int o = 0;
    for (int r = 0; r < R_; r++) { relOff[r] = o; o += relCnt[r]; }
  }
  __syncthreads();
  for (int e = tid; e < EPG; e += 256) {
    int s = ei[base + e] - nbase;
    int d = ei[E_ + base + e] - nbase;
    int r = et[base + e];
    float norm = 1.0f / (float)cnt[d * R_ + r];
    _Float16 hn = (_Float16)norm;
    unsigned short hb; __builtin_memcpy(&hb, &hn, 2);
    uint32_t rec = (uint32_t)s | ((uint32_t)d << 8) | ((uint32_t)hb << 16);
    int pos = atomicAdd(&cur[r], 1);
    ebuf[base + relOff[r] + pos] = rec;
  }
  if (tid < R_) { ecnt[g * R_ + tid] = relCnt[tid]; eoff[g * R_ + tid] = base + relOff[tid]; }
}

// ---------------- prepass 2: stage W1|root1, W2|root2 into B-fragment-native f16 layout --------
// flat = ((((l*9+r)*8 + nt)*4 + kt)*64 + lane)*8 + j ; value = W[r][k= kt*32+(lane>>4)*8+j][n= nt*16+(lane&15)]
__global__ __launch_bounds__(256) void k_wstage(const float* __restrict__ W1, const float* __restrict__ root1,
                                                const float* __restrict__ W2, const float* __restrict__ root2,
                                                _Float16* __restrict__ wf) {
  int t = blockIdx.x * 256 + threadIdx.x;
  if (t >= 2 * 9 * 8 * 4 * 64 * 8) return;
  int j = t & 7;
  int rest = t >> 3;
  int lane = rest & 63; rest >>= 6;
  int kt = rest & 3;    rest >>= 2;
  int nt = rest & 7;    rest >>= 3;
  int r = rest % 9;
  int l = rest / 9;
  int k = kt * 32 + (lane >> 4) * 8 + j;
  int n = nt * 16 + (lane & 15);
  const float* Wl = (l == 0) ? W1 : W2;
  const float* rl = (l == 0) ? root1 : root2;
  float v = (r < 8) ? Wl[(r * F_ + k) * F_ + n] : rl[k * F_ + n];
  wf[t] = (_Float16)v;
}

// ---------------- prepass 3: message representation [250][128] fp32 ----------------
__global__ __launch_bounds__(128) void k_msgr(const float* __restrict__ message, const float* __restrict__ embed,
                                              const float* __restrict__ cw, const float* __restrict__ cb,
                                              const float* __restrict__ mw, const float* __restrict__ mb,
                                              float* __restrict__ msgr) {
  __shared__ float comb[256];
  int g = blockIdx.x, tid = threadIdx.x;
  int tok = (int)message[g * 2];
  float cont = message[g * 2 + 1];
  comb[tid] = embed[tok * F_ + tid];
  float ce = cont * cw[tid] + cb[tid];
  comb[F_ + tid] = ce > 0.0f ? ce : 0.0f;
  __syncthreads();
  float acc = mb[tid];
#pragma unroll 8
  for (int k = 0; k < 256; k++) acc += comb[k] * mw[k * F_ + tid];
  msgr[g * F_ + tid] = acc > 0.0f ? acc : 0.0f;
}

// ---------------- main: one workgroup = one graph, both RGCN layers + scoring fused ----------------
__device__ __forceinline__ f16x8 loadA_S(const float* Sp, int row, int koff) {
  const f32x4 p0 = *((const f32x4*)(Sp + row * SROW + koff));
  const f32x4 p1 = *((const f32x4*)(Sp + row * SROW + koff + 4));
  f16x8 a;
  a[0] = (_Float16)p0[0]; a[1] = (_Float16)p0[1]; a[2] = (_Float16)p0[2]; a[3] = (_Float16)p0[3];
  a[4] = (_Float16)p1[0]; a[5] = (_Float16)p1[1]; a[6] = (_Float16)p1[2]; a[7] = (_Float16)p1[3];
  return a;
}

__global__ __launch_bounds__(512, 2) void k_main(const float* __restrict__ x,
                                                 const uint32_t* __restrict__ ebuf,
                                                 const int* __restrict__ ecnt, const int* __restrict__ eoff,
                                                 const _Float16* __restrict__ wf,
                                                 const float* __restrict__ b1, const float* __restrict__ b2,
                                                 const float* __restrict__ msgr, float* __restrict__ out) {
  __shared__ _Float16 hbuf[P_ * HROW];   // 54400 B
  __shared__ float    S[P_ * SROW];      // 105600 B
  __shared__ float    msgS[F_];          // 512 B   -> total 160512 <= 163840
  int g = blockIdx.x, tid = threadIdx.x;
  int lane = tid & 63, wave = tid >> 6;
  int quad = lane >> 4, lc = lane & 15;

  // stage x -> hbuf (f16)
  for (int i = tid; i < P_ * 32; i += 512) {
    int row = i >> 5, c4 = i & 31;
    const float4 v = ((const float4*)x)[(g * P_ + row) * 32 + c4];
    f16x4 pk = { (_Float16)v.x, (_Float16)v.y, (_Float16)v.z, (_Float16)v.w };
    *((f16x4*)&hbuf[row * HROW + c4 * 4]) = pk;
  }
  if (tid < F_) msgS[tid] = msgr[g * F_ + tid];
  __syncthreads();

  // wave -> M-tiles (13 tiles of 16 rows cover 200 rows; waves 0..4 get a second tile)
  int mt0 = wave;
  int mt1 = wave + 8;
  bool hasMt1 = (mt1 < 13);
  int rA0 = mt0 * 16 + lc; if (rA0 > P_ - 1) rA0 = P_ - 1;
  int rA1 = hasMt1 ? (mt1 * 16 + lc) : rA0; if (rA1 > P_ - 1) rA1 = P_ - 1;
  int kq = quad * 8;
  int sub = tid >> 7, fE = tid & 127;

  for (int l = 0; l < 2; l++) {
    f32x4 acc0[8], acc1[8];
#pragma unroll
    for (int nt = 0; nt < 8; nt++) {
      acc0[nt] = f32x4{0.0f, 0.0f, 0.0f, 0.0f};
      acc1[nt] = f32x4{0.0f, 0.0f, 0.0f, 0.0f};
    }
    const _Float16* wl = wf + l * (9 * 8 * 4 * 64 * 8);
    for (int r = 0; r < 9; r++) {
      if (r < 8) {
        __syncthreads();                                   // previous MFMA readers of S done
        for (int i = tid; i < P_ * SROW; i += 512) S[i] = 0.0f;
        __syncthreads();
        int nE = ecnt[g * R_ + r];
        int base = eoff[g * R_ + r];
        for (int e = sub; e < nE; e += 4) {                // 4 edges x 128 features per iter
          uint32_t rec = ebuf[base + e];
          int s = rec & 255, d = (rec >> 8) & 255;
          unsigned short hb = (unsigned short)(rec >> 16);
          _Float16 hv; __builtin_memcpy(&hv, &hb, 2);
          float val = (float)hbuf[s * HROW + fE] * (float)hv;
          atomicAdd(&S[d * SROW + fE], val);
        }
        __syncthreads();
      }
      // out += A @ W_r ; A = S (r<8, f32->f16) or h (r==8, root term)
      const _Float16* wr = wl + r * (8 * 4 * 64 * 8);
#pragma unroll
      for (int kt = 0; kt < 4; kt++) {
        f16x8 a0, a1;
        if (r < 8) {
          a0 = loadA_S(S, rA0, kt * 32 + kq);
          a1 = hasMt1 ? loadA_S(S, rA1, kt * 32 + kq) : a0;
        } else {
          a0 = *((const f16x8*)&hbuf[rA0 * HROW + kt * 32 + kq]);
          a1 = hasMt1 ? *((const f16x8*)&hbuf[rA1 * HROW + kt * 32 + kq]) : a0;
        }
#pragma unroll
        for (int nt = 0; nt < 8; nt++) {
          f16x8 b = *((const f16x8*)(wr + ((nt * 4 + kt) * 64 + lane) * 8));
          acc0[nt] = __builtin_amdgcn_mfma_f32_16x16x32_f16(a0, b, acc0[nt], 0, 0, 0);
          if (hasMt1)
            acc1[nt] = __builtin_amdgcn_mfma_f32_16x16x32_f16(a1, b, acc1[nt], 0, 0, 0);
        }
      }
    }
    __syncthreads();   // all waves done reading S/hbuf before overwrite
    if (l == 0) {
      // h' = relu(out + b1) -> hbuf (f16)
#pragma unroll
      for (int nt = 0; nt < 8; nt++) {
        int col = nt * 16 + lc;
        float bias = b1[col];
#pragma unroll
        for (int reg = 0; reg < 4; reg++) {
          int row = mt0 * 16 + quad * 4 + reg;
          float v = acc0[nt][reg] + bias; v = v > 0.0f ? v : 0.0f;
          if (row < P_) hbuf[row * HROW + col] = (_Float16)v;
          if (hasMt1) {
            int row1 = mt1 * 16 + quad * 4 + reg;
            float v1 = acc1[nt][reg] + bias; v1 = v1 > 0.0f ? v1 : 0.0f;
            if (row1 < P_) hbuf[row1 * HROW + col] = (_Float16)v1;
          }
        }
      }
      __syncthreads();
    } else {
      // node_emb = out + b2 -> S (f32), then score against msgS
#pragma unroll
      for (int nt = 0; nt < 8; nt++) {
        int col = nt * 16 + lc;
        float bias = b2[col];
#pragma unroll
        for (int reg = 0; reg < 4; reg++) {
          int row = mt0 * 16 + quad * 4 + reg;
          if (row < P_) S[row * SROW + col] = acc0[nt][reg] + bias;
          if (hasMt1) {
            int row1 = mt1 * 16 + quad * 4 + reg;
            if (row1 < P_) S[row1 * SROW + col] = acc1[nt][reg] + bias;
          }
        }
      }
      __syncthreads();
      for (int row = tid; row < P_; row += 512) {
        float dsum = 0.0f;
#pragma unroll 16
        for (int c = 0; c < F_; c++) dsum += S[row * SROW + c] * msgS[c];
        out[g * P_ + row] = dsum;
      }
    }
  }
}

extern "C" void kernel_launch(void* const* d_in, const int* in_sizes, int n_in,
                              void* d_out, int out_size, void* d_ws, size_t ws_size,
                              hipStream_t stream) {
  const float* message = (const float*)d_in[0];
  const float* x       = (const float*)d_in[1];
  const int*   ei      = (const int*)d_in[2];
  const int*   et      = (const int*)d_in[3];
  const float* W1      = (const float*)d_in[6];
  const float* root1   = (const float*)d_in[7];
  const float* b1      = (const float*)d_in[8];
  const float* W2      = (const float*)d_in[9];
  const float* root2   = (const float*)d_in[10];
  const float* b2      = (const float*)d_in[11];
  const float* embed   = (const float*)d_in[12];
  const float* cw      = (const float*)d_in[13];
  const float* cb      = (const float*)d_in[14];
  const float* mw      = (const float*)d_in[15];
  const float* mb      = (const float*)d_in[16];

  char* ws = (char*)d_ws;
  uint32_t*  ebuf  = (uint32_t*)(ws);                 // 3,200,000 B
  int*       ecnt  = (int*)(ws + 3200000);            // 8,000 B
  int*       eoff  = (int*)(ws + 3208000);            // 8,000 B
  float*     msgr  = (float*)(ws + 3216000);          // 128,000 B
  _Float16*  wfrag = (_Float16*)(ws + 3344000);       // 589,824 B  (total ~3.93 MB)
  float*     out   = (float*)d_out;

  hipLaunchKernelGGL(k_bucket, dim3(G_), dim3(256), 0, stream, ei, et, ebuf, ecnt, eoff);
  hipLaunchKernelGGL(k_wstage, dim3(1152), dim3(256), 0, stream, W1, root1, W2, root2, wfrag);
  hipLaunchKernelGGL(k_msgr, dim3(G_), dim3(128), 0, stream, message, embed, cw, cb, mw, mb, msgr);
  hipLaunchKernelGGL(k_main, dim3(G_), dim3(512), 0, stream, x, ebuf, ecnt, eoff, wfrag, b1, b2, msgr, out);
}

// Round 2
// 230.834 us; speedup vs baseline: 17.5432x; 17.5432x over previous
//
#include <hip/hip_runtime.h>
#include <stdint.h>

#define G_   250
#define P_   200
#define EPG  3200
#define E_   800000
#define F_   128
#define R_   8
#define HROW 136   // f16 elems per row (272 B stride = 68 banks -> balanced for b128 reads)
#define NKEY (R_ * P_)   // 1600 (rel,dst) buckets per graph

typedef _Float16 f16x8 __attribute__((ext_vector_type(8)));
typedef _Float16 f16x4 __attribute__((ext_vector_type(4)));
typedef float    f32x4 __attribute__((ext_vector_type(4)));

// ---------------- prepass 1: CSR by (relation, dst) within each graph ----------------
// edges contiguous per graph; src/dst local < 200. Output: csr[g*3200 + k] = src (ushort),
// sorted by key=(r*200+d); offs[g*1601 + key] = bucket start, offs[...1600] = 3200.
__global__ __launch_bounds__(256) void k_csr(const int* __restrict__ ei, const int* __restrict__ et,
                                             unsigned short* __restrict__ csr, int* __restrict__ offs) {
  __shared__ int cnt[NKEY];
  __shared__ int offsS[NKEY + 1];
  __shared__ int cur[NKEY];
  __shared__ int chunkTot[200];
  int g = blockIdx.x, tid = threadIdx.x;
  for (int i = tid; i < NKEY; i += 256) { cnt[i] = 0; cur[i] = 0; }
  __syncthreads();
  int base = g * EPG, nbase = g * P_;
  for (int e = tid; e < EPG; e += 256) {
    int d = ei[E_ + base + e] - nbase;
    int r = et[base + e];
    atomicAdd(&cnt[r * P_ + d], 1);
  }
  __syncthreads();
  // exclusive scan over 1600 buckets: 200 chunks of 8
  if (tid < 200) {
    int s = 0;
    for (int i = 0; i < 8; i++) { int c = cnt[tid * 8 + i]; offsS[tid * 8 + i] = s; s += c; }
    chunkTot[tid] = s;
  }
  __syncthreads();
  if (tid == 0) {
    int run = 0;
    for (int j = 0; j < 200; j++) { int c = chunkTot[j]; chunkTot[j] = run; run += c; }
    offsS[NKEY] = EPG;
  }
  __syncthreads();
  if (tid < 200) {
    int add = chunkTot[tid];
    for (int i = 0; i < 8; i++) offsS[tid * 8 + i] += add;
  }
  __syncthreads();
  for (int i = tid; i < NKEY + 1; i += 256) offs[g * (NKEY + 1) + i] = offsS[i];
  for (int e = tid; e < EPG; e += 256) {
    int s = ei[base + e] - nbase;
    int d = ei[E_ + base + e] - nbase;
    int r = et[base + e];
    int key = r * P_ + d;
    int pos = atomicAdd(&cur[key], 1);
    csr[base + offsS[key] + pos] = (unsigned short)s;
  }
}

// ---------------- prepass 2: stage W1|root1, W2|root2 into B-fragment-native f16 layout --------
// flat = ((((l*9+r)*8 + nt)*4 + kt)*64 + lane)*8 + j ; value = W[r][k= kt*32+(lane>>4)*8+j][n= nt*16+(lane&15)]
__global__ __launch_bounds__(256) void k_wstage(const float* __restrict__ W1, const float* __restrict__ root1,
                                                const float* __restrict__ W2, const float* __restrict__ root2,
                                                _Float16* __restrict__ wf) {
  int t = blockIdx.x * 256 + threadIdx.x;
  if (t >= 2 * 9 * 8 * 4 * 64 * 8) return;
  int j = t & 7;
  int rest = t >> 3;
  int lane = rest & 63; rest >>= 6;
  int kt = rest & 3;    rest >>= 2;
  int nt = rest & 7;    rest >>= 3;
  int r = rest % 9;
  int l = rest / 9;
  int k = kt * 32 + (lane >> 4) * 8 + j;
  int n = nt * 16 + (lane & 15);
  const float* Wl = (l == 0) ? W1 : W2;
  const float* rl = (l == 0) ? root1 : root2;
  float v = (r < 8) ? Wl[(r * F_ + k) * F_ + n] : rl[k * F_ + n];
  wf[t] = (_Float16)v;
}

// ---------------- prepass 3: message repr [250][132] fp32; slot 128 = dot(b2, msgr) -------------
__global__ __launch_bounds__(128) void k_msgr(const float* __restrict__ message, const float* __restrict__ embed,
                                              const float* __restrict__ cw, const float* __restrict__ cb,
                                              const float* __restrict__ mw, const float* __restrict__ mb,
                                              const float* __restrict__ b2, float* __restrict__ msgr) {
  __shared__ float comb[256];
  __shared__ float red[128];
  int g = blockIdx.x, tid = threadIdx.x;
  int tok = (int)message[g * 2];
  float cont = message[g * 2 + 1];
  comb[tid] = embed[tok * F_ + tid];
  float ce = cont * cw[tid] + cb[tid];
  comb[F_ + tid] = ce > 0.0f ? ce : 0.0f;
  __syncthreads();
  float acc = mb[tid];
#pragma unroll 8
  for (int k = 0; k < 256; k++) acc += comb[k] * mw[k * F_ + tid];
  float val = acc > 0.0f ? acc : 0.0f;
  msgr[g * 132 + tid] = val;
  red[tid] = val * b2[tid];
  __syncthreads();
  for (int s2 = 64; s2 > 0; s2 >>= 1) {
    if (tid < s2) red[tid] += red[tid + s2];
    __syncthreads();
  }
  if (tid == 0) msgr[g * 132 + 128] = red[0];
}

// ---------------- main: one workgroup = one graph, both layers fused ----------------
// Per (layer, rel): stage 32KB B into LDS + CSR-aggregate S (f16, no atomics), then MFMA.
__global__ __launch_bounds__(512, 1) void k_main(const float* __restrict__ x,
                                                 const unsigned short* __restrict__ csr,
                                                 const int* __restrict__ offs,
                                                 const _Float16* __restrict__ wf,
                                                 const float* __restrict__ b1,
                                                 const float* __restrict__ msgr, float* __restrict__ out) {
  __shared__ __attribute__((aligned(16))) _Float16 hbuf[P_ * HROW];   // 54400 B
  __shared__ __attribute__((aligned(16))) _Float16 S[P_ * HROW];      // 54400 B
  __shared__ __attribute__((aligned(16))) _Float16 Bstage[8 * 4 * 64 * 8]; // 32768 B
  __shared__ int offsS[NKEY + 1];                                     // 6404 B
  __shared__ unsigned short csrS[EPG];                                // 6400 B
  __shared__ float msgS[132];                                         // 528 B -> 154900 B total
  int g = blockIdx.x, tid = threadIdx.x;
  int lane = tid & 63, wave = tid >> 6, quad = lane >> 4, lc = lane & 15;

  // stage x -> hbuf (f16), csr/offs/msg -> LDS
  for (int i = tid; i < P_ * 32; i += 512) {
    int row = i >> 5, c4 = i & 31;
    const float4 v = ((const float4*)x)[(g * P_ + row) * 32 + c4];
    f16x4 pk = { (_Float16)v.x, (_Float16)v.y, (_Float16)v.z, (_Float16)v.w };
    *((f16x4*)&hbuf[row * HROW + c4 * 4]) = pk;
  }
  for (int i = tid; i < NKEY + 1; i += 512) offsS[i] = offs[g * (NKEY + 1) + i];
  for (int i = tid; i < EPG; i += 512) csrS[i] = csr[g * EPG + i];
  if (tid < F_ + 1) msgS[tid] = msgr[g * 132 + tid];
  __syncthreads();

  // wave -> M-tiles (13 tiles of 16 rows cover 200; waves 0..4 take a second tile)
  int mt0 = wave, mt1 = wave + 8;
  bool hasMt1 = (mt1 < 13);
  int rA0 = mt0 * 16 + lc; if (rA0 > P_ - 1) rA0 = P_ - 1;
  int rA1 = hasMt1 ? (mt1 * 16 + lc) : rA0; if (rA1 > P_ - 1) rA1 = P_ - 1;
  int kq = quad * 8;
  // aggregation: 16 threads (f16x8 each) per dst row, 32 rows in flight
  int dsub = tid >> 4;
  int c8 = (tid & 15) * 8;

  for (int l = 0; l < 2; l++) {
    f32x4 acc0[8], acc1[8];
#pragma unroll
    for (int nt = 0; nt < 8; nt++) {
      acc0[nt] = f32x4{0.0f, 0.0f, 0.0f, 0.0f};
      acc1[nt] = f32x4{0.0f, 0.0f, 0.0f, 0.0f};
    }
    const _Float16* wl = wf + l * (9 * 8 * 4 * 64 * 8);
    for (int r = 0; r < 9; r++) {
      __syncthreads();   // previous MFMA done reading S/Bstage
      {  // stage B_r (32 KB) global -> LDS, coalesced 16 B per thread x4
        const f16x8* src = (const f16x8*)(wl + r * (8 * 4 * 64 * 8));
        f16x8* dstv = (f16x8*)Bstage;
#pragma unroll
        for (int i = 0; i < 4; i++) dstv[tid + i * 512] = src[tid + i * 512];
      }
      if (r < 8) {  // S[d][:] = mean of hbuf[src][:] over CSR bucket (r,d)
        for (int d = dsub; d < P_; d += 32) {
          int o0 = offsS[r * P_ + d], o1 = offsS[r * P_ + d + 1];
          float a[8];
#pragma unroll
          for (int jj = 0; jj < 8; jj++) a[jj] = 0.0f;
          for (int e = o0; e < o1; e++) {
            int s = csrS[e];
            f16x8 hv = *((const f16x8*)&hbuf[s * HROW + c8]);
#pragma unroll
            for (int jj = 0; jj < 8; jj++) a[jj] += (float)hv[jj];
          }
          float nrm = (o1 > o0) ? 1.0f / (float)(o1 - o0) : 0.0f;
          f16x8 o;
#pragma unroll
          for (int jj = 0; jj < 8; jj++) o[jj] = (_Float16)(a[jj] * nrm);
          *((f16x8*)&S[d * HROW + c8]) = o;
        }
      }
      __syncthreads();
      const _Float16* Ap = (r < 8) ? S : hbuf;   // root relation uses h directly
#pragma unroll
      for (int kt = 0; kt < 4; kt++) {
        f16x8 a0 = *((const f16x8*)&Ap[rA0 * HROW + kt * 32 + kq]);
        f16x8 a1 = *((const f16x8*)&Ap[rA1 * HROW + kt * 32 + kq]);
#pragma unroll
        for (int nt = 0; nt < 8; nt++) {
          f16x8 b = *((const f16x8*)&Bstage[((nt * 4 + kt) * 64 + lane) * 8]);
          acc0[nt] = __builtin_amdgcn_mfma_f32_16x16x32_f16(a0, b, acc0[nt], 0, 0, 0);
          if (hasMt1)
            acc1[nt] = __builtin_amdgcn_mfma_f32_16x16x32_f16(a1, b, acc1[nt], 0, 0, 0);
        }
      }
    }
    __syncthreads();   // all MFMA readers of hbuf done before overwrite
    if (l == 0) {
      // h' = relu(acc + b1) -> hbuf (f16); C layout: col=lane&15, row=quad*4+reg (m89-verified)
#pragma unroll
      for (int nt = 0; nt < 8; nt++) {
        int col = nt * 16 + lc;
        float bias = b1[col];
#pragma unroll
        for (int reg = 0; reg < 4; reg++) {
          int row = mt0 * 16 + quad * 4 + reg;
          float v = acc0[nt][reg] + bias; v = v > 0.0f ? v : 0.0f;
          hbuf[row * HROW + col] = (_Float16)v;   // row<128 always for mt0
          if (hasMt1) {
            int row1 = mt1 * 16 + quad * 4 + reg;
            float v1 = acc1[nt][reg] + bias; v1 = v1 > 0.0f ? v1 : 0.0f;
            if (row1 < P_) hbuf[row1 * HROW + col] = (_Float16)v1;
          }
        }
      }
    } else {
      // score = dot(acc + b2, msg) = dot(acc,msg) + dot(b2,msg); in-register shfl reduce
      float db2 = msgS[F_];
#pragma unroll
      for (int reg = 0; reg < 4; reg++) {
        float p0 = 0.0f, p1 = 0.0f;
#pragma unroll
        for (int nt = 0; nt < 8; nt++) {
          float m = msgS[nt * 16 + lc];
          p0 += acc0[nt][reg] * m;
          if (hasMt1) p1 += acc1[nt][reg] * m;
        }
        p0 += __shfl_xor(p0, 8, 16); p0 += __shfl_xor(p0, 4, 16);
        p0 += __shfl_xor(p0, 2, 16); p0 += __shfl_xor(p0, 1, 16);
        int row0 = mt0 * 16 + quad * 4 + reg;
        if (lc == 0) out[g * P_ + row0] = p0 + db2;
        if (hasMt1) {
          p1 += __shfl_xor(p1, 8, 16); p1 += __shfl_xor(p1, 4, 16);
          p1 += __shfl_xor(p1, 2, 16); p1 += __shfl_xor(p1, 1, 16);
          int row1 = mt1 * 16 + quad * 4 + reg;
          if (lc == 0 && row1 < P_) out[g * P_ + row1] = p1 + db2;
        }
      }
    }
  }
}

extern "C" void kernel_launch(void* const* d_in, const int* in_sizes, int n_in,
                              void* d_out, int out_size, void* d_ws, size_t ws_size,
                              hipStream_t stream) {
  const float* message = (const float*)d_in[0];
  const float* x       = (const float*)d_in[1];
  const int*   ei      = (const int*)d_in[2];
  const int*   et      = (const int*)d_in[3];
  const float* W1      = (const float*)d_in[6];
  const float* root1   = (const float*)d_in[7];
  const float* b1      = (const float*)d_in[8];
  const float* W2      = (const float*)d_in[9];
  const float* root2   = (const float*)d_in[10];
  const float* b2      = (const float*)d_in[11];
  const float* embed   = (const float*)d_in[12];
  const float* cw      = (const float*)d_in[13];
  const float* cb      = (const float*)d_in[14];
  const float* mw      = (const float*)d_in[15];
  const float* mb      = (const float*)d_in[16];

  char* ws = (char*)d_ws;
  unsigned short* csr  = (unsigned short*)(ws);          // 1,600,000 B
  int*            offs = (int*)(ws + 1600000);           // 250*1601*4 = 1,601,000 B
  float*          msgr = (float*)(ws + 3201024);         // 132,000 B (16-aligned)
  _Float16*       wfrag= (_Float16*)(ws + 3333120);      // 589,824 B (16-aligned); total ~3.93 MB
  float*          out  = (float*)d_out;

  hipLaunchKernelGGL(k_csr, dim3(G_), dim3(256), 0, stream, ei, et, csr, offs);
  hipLaunchKernelGGL(k_wstage, dim3(1152), dim3(256), 0, stream, W1, root1, W2, root2, wfrag);
  hipLaunchKernelGGL(k_msgr, dim3(G_), dim3(128), 0, stream, message, embed, cw, cb, mw, mb, b2, msgr);
  hipLaunchKernelGGL(k_main, dim3(G_), dim3(512), 0, stream, x, csr, offs, wfrag, b1, msgr, out);
}

// Round 3
// 222.748 us; speedup vs baseline: 18.1801x; 1.0363x over previous
//
#include <hip/hip_runtime.h>
#include <stdint.h>

#define G_   250
#define P_   200
#define EPG  3200
#define E_   800000
#define F_   128
#define R_   8
#define HROW 136   // f16 elems per row; 272 B stride -> 2-way LDS aliasing (free)
#define NKEY (R_ * P_)   // 1600 (rel,dst) buckets

typedef _Float16 f16x8 __attribute__((ext_vector_type(8)));
typedef _Float16 f16x4 __attribute__((ext_vector_type(4)));
typedef float    f32x4 __attribute__((ext_vector_type(4)));

// ---------------- prepass: stage W1|root1, W2|root2 into B-fragment-native f16 layout --------
// flat = ((((l*9+r)*8 + nt)*4 + kt)*64 + lane)*8 + j ; value = W[r][k= kt*32+(lane>>4)*8+j][n= nt*16+(lane&15)]
__global__ __launch_bounds__(256) void k_wstage(const float* __restrict__ W1, const float* __restrict__ root1,
                                                const float* __restrict__ W2, const float* __restrict__ root2,
                                                _Float16* __restrict__ wf) {
  int t = blockIdx.x * 256 + threadIdx.x;
  if (t >= 2 * 9 * 8 * 4 * 64 * 8) return;
  int j = t & 7;
  int rest = t >> 3;
  int lane = rest & 63; rest >>= 6;
  int kt = rest & 3;    rest >>= 2;
  int nt = rest & 7;    rest >>= 3;
  int r = rest % 9;
  int l = rest / 9;
  int k = kt * 32 + (lane >> 4) * 8 + j;
  int n = nt * 16 + (lane & 15);
  const float* Wl = (l == 0) ? W1 : W2;
  const float* rl = (l == 0) ? root1 : root2;
  float v = (r < 8) ? Wl[(r * F_ + k) * F_ + n] : rl[k * F_ + n];
  wf[t] = (_Float16)v;
}

// ---------------- main: one workgroup = one graph; CSR + msg-repr + both layers fused ----------
__global__ __launch_bounds__(512, 2) void k_main(
    const float* __restrict__ x, const int* __restrict__ ei, const int* __restrict__ et,
    const _Float16* __restrict__ wf, const float* __restrict__ b1, const float* __restrict__ b2,
    const float* __restrict__ message, const float* __restrict__ embed,
    const float* __restrict__ cw, const float* __restrict__ cb,
    const float* __restrict__ mw, const float* __restrict__ mb,
    float* __restrict__ out) {
  __shared__ __attribute__((aligned(16))) _Float16 hbuf[P_ * HROW];   // 54400 B
  __shared__ __attribute__((aligned(16))) _Float16 S[P_ * HROW];      // 54400 B
  __shared__ int offsS[NKEY + 1];                                     // 6404 B
  __shared__ unsigned short csrS[EPG];                                // 6400 B
  __shared__ float msgS[F_ + 1];                                      // 516 B  -> ~122.1 KB
  int g = blockIdx.x, tid = threadIdx.x;
  int lane = tid & 63, wave = tid >> 6, quad = lane >> 4, lc = lane & 15;

  // ---- setup: stage x -> hbuf (f16) ----
  for (int i = tid; i < P_ * 32; i += 512) {
    int row = i >> 5, c4 = i & 31;
    const float4 v = ((const float4*)x)[(g * P_ + row) * 32 + c4];
    f16x4 pk = { (_Float16)v.x, (_Float16)v.y, (_Float16)v.z, (_Float16)v.w };
    *((f16x4*)&hbuf[row * HROW + c4 * 4]) = pk;
  }
  // scratch aliases inside S (overwritten by aggregation later)
  int*   Sint     = (int*)S;
  int*   cnt      = Sint;               // [1600]
  int*   cur      = Sint + NKEY;        // [1600]
  int*   chunkTot = Sint + 2 * NKEY;    // [200]
  float* comb     = (float*)(Sint + 2 * NKEY + 200);   // [256]
  float* red      = comb + 256;                        // [512]

  for (int i = tid; i < NKEY; i += 512) { cnt[i] = 0; cur[i] = 0; }
  __syncthreads();
  int base = g * EPG, nbase = g * P_;
  for (int e = tid; e < EPG; e += 512) {
    int d = ei[E_ + base + e] - nbase;
    int r = et[base + e];
    atomicAdd(&cnt[r * P_ + d], 1);
  }
  if (tid < F_) {   // message combined features (independent of cnt)
    int tok = (int)message[g * 2];
    float cont = message[g * 2 + 1];
    comb[tid] = embed[tok * F_ + tid];
    float ce = cont * cw[tid] + cb[tid];
    comb[F_ + tid] = ce > 0.0f ? ce : 0.0f;
  }
  __syncthreads();
  if (tid < 200) {   // exclusive scan over 1600 buckets
    int s = 0;
    for (int i = 0; i < 8; i++) { int c = cnt[tid * 8 + i]; offsS[tid * 8 + i] = s; s += c; }
    chunkTot[tid] = s;
  }
  __syncthreads();
  if (tid == 0) {
    int run = 0;
    for (int j = 0; j < 200; j++) { int c = chunkTot[j]; chunkTot[j] = run; run += c; }
    offsS[NKEY] = EPG;
  }
  __syncthreads();
  if (tid < 200) {
    int add = chunkTot[tid];
    for (int i = 0; i < 8; i++) offsS[tid * 8 + i] += add;
  }
  {   // message matmul partials: 4 segs x 128 cols
    int col = tid & 127, seg = tid >> 7;
    float acc = 0.0f;
#pragma unroll 8
    for (int k = seg * 64; k < seg * 64 + 64; k++) acc += comb[k] * mw[k * F_ + col];
    red[tid] = acc;
  }
  __syncthreads();
  // CSR scatter (needs finalized offsS; uses cur atomics)
  for (int e = tid; e < EPG; e += 512) {
    int s = ei[base + e] - nbase;
    int d = ei[E_ + base + e] - nbase;
    int r = et[base + e];
    int key = r * P_ + d;
    int pos = atomicAdd(&cur[key], 1);
    csrS[offsS[key] + pos] = (unsigned short)s;
  }
  if (tid < F_) {
    float a = mb[tid] + red[tid] + red[128 + tid] + red[256 + tid] + red[384 + tid];
    a = a > 0.0f ? a : 0.0f;
    msgS[tid] = a;
    comb[tid] = a * b2[tid];   // for db2 = dot(msg, b2)
  }
  __syncthreads();
  if (tid < 64) comb[tid] += comb[tid + 64];
  __syncthreads();
  if (tid < 32) comb[tid] += comb[tid + 32];
  __syncthreads();
  if (tid < 16) comb[tid] += comb[tid + 16];
  __syncthreads();
  if (tid < 8) comb[tid] += comb[tid + 8];
  __syncthreads();
  if (tid < 4) comb[tid] += comb[tid + 4];
  __syncthreads();
  if (tid == 0) msgS[F_] = comb[0] + comb[1] + comb[2] + comb[3];
  __syncthreads();

  // ---- main fused loop ----
  int mgrp = wave >> 1, ngrp = wave & 1;   // 4 x 2 wave grid
  int dsub = tid >> 4;                      // 32 row-groups of 16 threads
  int c8 = (tid & 15) * 8;

  for (int l = 0; l < 2; l++) {
    f32x4 acc[4][4];   // [mtj][ntj]
#pragma unroll
    for (int a = 0; a < 4; a++)
#pragma unroll
      for (int b = 0; b < 4; b++) acc[a][b] = f32x4{0.0f, 0.0f, 0.0f, 0.0f};
    const _Float16* wl = wf + l * (9 * 8 * 4 * 64 * 8);
    for (int r = 0; r < 9; r++) {
      // prefetch this wave's B-fragments (global, in flight across aggregation)
      f16x8 Bf[4][4];   // [ntj][kt]
      const _Float16* wr = wl + r * (8 * 4 * 64 * 8);
#pragma unroll
      for (int ntj = 0; ntj < 4; ntj++)
#pragma unroll
        for (int kt = 0; kt < 4; kt++)
          Bf[ntj][kt] = *((const f16x8*)(wr + (((ngrp * 4 + ntj) * 4 + kt) * 64 + lane) * 8));
      __syncthreads();   // MFMA of r-1 done reading S
      if (r < 8) {       // dual-chain CSR aggregation into S (f16)
        int rbase = r * P_;
        for (int d0 = dsub; d0 < P_; d0 += 64) {
          int d1 = d0 + 32;
          bool h1 = d1 < P_;
          int oa0 = offsS[rbase + d0], oa1 = offsS[rbase + d0 + 1];
          int ob0 = h1 ? offsS[rbase + d1] : 0, ob1 = h1 ? offsS[rbase + d1 + 1] : 0;
          float a0[8], a1[8];
#pragma unroll
          for (int j = 0; j < 8; j++) { a0[j] = 0.0f; a1[j] = 0.0f; }
          int na = oa1 - oa0, nb = ob1 - ob0;
          int nm = na > nb ? na : nb;
          for (int t = 0; t < nm; t++) {
            if (t < na) {
              int s = csrS[oa0 + t];
              f16x8 hv = *((const f16x8*)&hbuf[s * HROW + c8]);
#pragma unroll
              for (int j = 0; j < 8; j++) a0[j] += (float)hv[j];
            }
            if (t < nb) {
              int s = csrS[ob0 + t];
              f16x8 hv = *((const f16x8*)&hbuf[s * HROW + c8]);
#pragma unroll
              for (int j = 0; j < 8; j++) a1[j] += (float)hv[j];
            }
          }
          float n0 = na > 0 ? 1.0f / (float)na : 0.0f;
          f16x8 o0;
#pragma unroll
          for (int j = 0; j < 8; j++) o0[j] = (_Float16)(a0[j] * n0);
          *((f16x8*)&S[d0 * HROW + c8]) = o0;
          if (h1) {
            float n1 = nb > 0 ? 1.0f / (float)nb : 0.0f;
            f16x8 o1;
#pragma unroll
            for (int j = 0; j < 8; j++) o1[j] = (_Float16)(a1[j] * n1);
            *((f16x8*)&S[d1 * HROW + c8]) = o1;
          }
        }
      }
      __syncthreads();   // S ready (and B arrived)
      const _Float16* Ap = (r < 8) ? S : hbuf;   // root relation uses h
#pragma unroll
      for (int mtj = 0; mtj < 4; mtj++) {
        int mt = mgrp + mtj * 4;
        if (mt < 13) {
          int rowA = mt * 16 + lc; rowA = rowA < P_ ? rowA : P_ - 1;
#pragma unroll
          for (int kt = 0; kt < 4; kt++) {
            f16x8 a = *((const f16x8*)&Ap[rowA * HROW + kt * 32 + quad * 8]);
#pragma unroll
            for (int ntj = 0; ntj < 4; ntj++)
              acc[mtj][ntj] = __builtin_amdgcn_mfma_f32_16x16x32_f16(a, Bf[ntj][kt], acc[mtj][ntj], 0, 0, 0);
          }
        }
      }
    }
    __syncthreads();   // all MFMA readers of hbuf/S done
    if (l == 0) {
      // h' = relu(acc + b1) -> hbuf; C layout col=lane&15, row=quad*4+reg
#pragma unroll
      for (int mtj = 0; mtj < 4; mtj++) {
        int mt = mgrp + mtj * 4;
        if (mt < 13) {
#pragma unroll
          for (int ntj = 0; ntj < 4; ntj++) {
            int col = (ngrp * 4 + ntj) * 16 + lc;
            float bias = b1[col];
#pragma unroll
            for (int reg = 0; reg < 4; reg++) {
              int row = mt * 16 + quad * 4 + reg;
              float v = acc[mtj][ntj][reg] + bias;
              v = v > 0.0f ? v : 0.0f;
              if (row < P_) hbuf[row * HROW + col] = (_Float16)v;
            }
          }
        }
      }
      __syncthreads();
    } else {
      // score: dot(node_emb, msg) + dot(b2, msg); two ngrp partials via LDS
      float* scoreS = (float*)S;   // S free after barrier
#pragma unroll
      for (int mtj = 0; mtj < 4; mtj++) {
        int mt = mgrp + mtj * 4;
        if (mt < 13) {
#pragma unroll
          for (int reg = 0; reg < 4; reg++) {
            float p = 0.0f;
#pragma unroll
            for (int ntj = 0; ntj < 4; ntj++)
              p += acc[mtj][ntj][reg] * msgS[(ngrp * 4 + ntj) * 16 + lc];
            p += __shfl_xor(p, 8, 16);
            p += __shfl_xor(p, 4, 16);
            p += __shfl_xor(p, 2, 16);
            p += __shfl_xor(p, 1, 16);
            int row = mt * 16 + quad * 4 + reg;
            if (lc == 0 && row < P_) scoreS[ngrp * P_ + row] = p;
          }
        }
      }
      __syncthreads();
      for (int i = tid; i < P_; i += 512)
        out[g * P_ + i] = scoreS[i] + scoreS[P_ + i] + msgS[F_];
    }
  }
}

extern "C" void kernel_launch(void* const* d_in, const int* in_sizes, int n_in,
                              void* d_out, int out_size, void* d_ws, size_t ws_size,
                              hipStream_t stream) {
  const float* message = (const float*)d_in[0];
  const float* x       = (const float*)d_in[1];
  const int*   ei      = (const int*)d_in[2];
  const int*   et      = (const int*)d_in[3];
  const float* W1      = (const float*)d_in[6];
  const float* root1   = (const float*)d_in[7];
  const float* b1      = (const float*)d_in[8];
  const float* W2      = (const float*)d_in[9];
  const float* root2   = (const float*)d_in[10];
  const float* b2      = (const float*)d_in[11];
  const float* embed   = (const float*)d_in[12];
  const float* cw      = (const float*)d_in[13];
  const float* cb      = (const float*)d_in[14];
  const float* mw      = (const float*)d_in[15];
  const float* mb      = (const float*)d_in[16];

  _Float16* wfrag = (_Float16*)d_ws;   // 589,824 B
  float*    out   = (float*)d_out;

  hipLaunchKernelGGL(k_wstage, dim3(1152), dim3(256), 0, stream, W1, root1, W2, root2, wfrag);
  hipLaunchKernelGGL(k_main, dim3(G_), dim3(512), 0, stream, x, ei, et, wfrag, b1, b2,
                     message, embed, cw, cb, mw, mb, out);
}

// Round 4
// 207.146 us; speedup vs baseline: 19.5493x; 1.0753x over previous
//
#include <hip/hip_runtime.h>
#include <stdint.h>

#define G_   250
#define P_   200
#define EPG  3200
#define E_   800000
#define F_   128
#define R_   8
#define HROW 136   // f16 elems per row; 272 B stride, 16B-aligned rows
#define NKEY (R_ * P_)   // 1600 (rel,dst) buckets

typedef _Float16 f16x8 __attribute__((ext_vector_type(8)));
typedef _Float16 f16x4 __attribute__((ext_vector_type(4)));
typedef float    f32x4 __attribute__((ext_vector_type(4)));

// ---------------- prepass: stage W1|root1, W2|root2 into B-fragment-native f16 layout --------
// flat = ((((l*9+r)*8 + nt)*4 + kt)*64 + lane)*8 + j ; value = W[r][k= kt*32+(lane>>4)*8+j][n= nt*16+(lane&15)]
__global__ __launch_bounds__(256) void k_wstage(const float* __restrict__ W1, const float* __restrict__ root1,
                                                const float* __restrict__ W2, const float* __restrict__ root2,
                                                _Float16* __restrict__ wf) {
  int t = blockIdx.x * 256 + threadIdx.x;
  if (t >= 2 * 9 * 8 * 4 * 64 * 8) return;
  int j = t & 7;
  int rest = t >> 3;
  int lane = rest & 63; rest >>= 6;
  int kt = rest & 3;    rest >>= 2;
  int nt = rest & 7;    rest >>= 3;
  int r = rest % 9;
  int l = rest / 9;
  int k = kt * 32 + (lane >> 4) * 8 + j;
  int n = nt * 16 + (lane & 15);
  const float* Wl = (l == 0) ? W1 : W2;
  const float* rl = (l == 0) ? root1 : root2;
  float v = (r < 8) ? Wl[(r * F_ + k) * F_ + n] : rl[k * F_ + n];
  wf[t] = (_Float16)v;
}

// ---------------- main: one workgroup = one graph; CSR + msg-repr + both layers fused ----------
__global__ __launch_bounds__(512, 2) void k_main(
    const float* __restrict__ x, const int* __restrict__ ei, const int* __restrict__ et,
    const _Float16* __restrict__ wf, const float* __restrict__ b1, const float* __restrict__ b2,
    const float* __restrict__ message, const float* __restrict__ embed,
    const float* __restrict__ cw, const float* __restrict__ cb,
    const float* __restrict__ mw, const float* __restrict__ mb,
    float* __restrict__ out) {
  __shared__ __attribute__((aligned(16))) _Float16 hbuf[P_ * HROW];   // 54400 B
  __shared__ __attribute__((aligned(16))) _Float16 S[P_ * HROW];      // 54400 B
  __shared__ int offsS[NKEY + 1];                                     // 6404 B
  __shared__ unsigned short csrS[EPG];                                // 6400 B
  __shared__ float msgS[F_ + 1];                                      // 516 B  -> ~122.1 KB
  int g = blockIdx.x, tid = threadIdx.x;
  int lane = tid & 63, wave = tid >> 6, quad = lane >> 4, lc = lane & 15;

  // ---- setup scratch aliased inside S (dead until main loop) ----
  int*   Sint     = (int*)S;
  int*   cnt      = Sint;                    // [1600]
  int*   cur      = Sint + 1600;             // [1600]
  int*   chunkTot = Sint + 3200;             // [200]
  int*   scanA    = Sint + 3400;             // [256]
  int*   scanB    = Sint + 3656;             // [256]
  float* comb     = (float*)(Sint + 3912);   // [256]
  float* red      = comb + 256;              // [512]
  int*   eRec     = (int*)(red + 512);       // [3200]  (total 7880 ints = 31.5 KB < 54.4 KB)

  // stage x -> hbuf (f16)
  for (int i = tid; i < P_ * 32; i += 512) {
    int row = i >> 5, c4 = i & 31;
    const float4 v = ((const float4*)x)[(g * P_ + row) * 32 + c4];
    f16x4 pk = { (_Float16)v.x, (_Float16)v.y, (_Float16)v.z, (_Float16)v.w };
    *((f16x4*)&hbuf[row * HROW + c4 * 4]) = pk;
  }
  for (int i = tid; i < NKEY; i += 512) { cnt[i] = 0; cur[i] = 0; }
  if (tid < F_) {   // message combined features
    int tok = (int)message[g * 2];
    float cont = message[g * 2 + 1];
    comb[tid] = embed[tok * F_ + tid];
    float ce = cont * cw[tid] + cb[tid];
    comb[F_ + tid] = ce > 0.0f ? ce : 0.0f;
  }
  __syncthreads();
  // edge ingest: pack records into LDS + count buckets
  int base = g * EPG, nbase = g * P_;
  for (int e = tid; e < EPG; e += 512) {
    int s = ei[base + e] - nbase;
    int d = ei[E_ + base + e] - nbase;
    int r = et[base + e];
    eRec[e] = s | (d << 8) | (r << 16);
    atomicAdd(&cnt[r * P_ + d], 1);
  }
  __syncthreads();
  if (tid < 200) {   // per-chunk serial scan (8 buckets each)
    int s = 0;
    for (int i = 0; i < 8; i++) { int c = cnt[tid * 8 + i]; offsS[tid * 8 + i] = s; s += c; }
    chunkTot[tid] = s;
    scanA[tid] = s;
  }
  __syncthreads();
  {  // Hillis-Steele inclusive scan of chunkTot[200]; 8 steps -> result back in scanA
    int* src = scanA; int* dst = scanB;
    for (int st = 1; st < 256; st <<= 1) {
      if (tid < 200) dst[tid] = src[tid] + (tid >= st ? src[tid - st] : 0);
      __syncthreads();
      int* tmp = src; src = dst; dst = tmp;
    }
  }
  if (tid < 200) {
    int add = scanA[tid] - chunkTot[tid];   // exclusive chunk base
    for (int i = 0; i < 8; i++) offsS[tid * 8 + i] += add;
  }
  if (tid == 0) offsS[NKEY] = EPG;
  {   // message matmul partials: 4 segs x 128 cols (comb ready since first barrier)
    int col = tid & 127, seg = tid >> 7;
    float acc = 0.0f;
#pragma unroll 8
    for (int k = seg * 64; k < seg * 64 + 64; k++) acc += comb[k] * mw[k * F_ + col];
    red[tid] = acc;
  }
  __syncthreads();
  // CSR scatter from LDS records
  for (int e = tid; e < EPG; e += 512) {
    int rec = eRec[e];
    int s = rec & 255, d = (rec >> 8) & 255, r = rec >> 16;
    int key = r * P_ + d;
    int pos = atomicAdd(&cur[key], 1);
    csrS[offsS[key] + pos] = (unsigned short)s;
  }
  if (tid < F_) {
    float a = mb[tid] + red[tid] + red[128 + tid] + red[256 + tid] + red[384 + tid];
    a = a > 0.0f ? a : 0.0f;
    msgS[tid] = a;
    comb[tid] = a * b2[tid];   // for db2 = dot(msg, b2)
  }
  __syncthreads();
  if (tid < 64) comb[tid] += comb[tid + 64];
  __syncthreads();
  if (tid < 32) comb[tid] += comb[tid + 32];
  __syncthreads();
  if (tid < 16) comb[tid] += comb[tid + 16];
  __syncthreads();
  if (tid == 0) {
    float s = 0.0f;
    for (int i = 0; i < 16; i++) s += comb[i];
    msgS[F_] = s;
  }

  // ---- main fused loop ----
  int mgrp = wave >> 1, ngrp = wave & 1;   // 4 x 2 wave grid
  int dsub = tid >> 4;                      // 32 row-groups of 16 threads
  int c8 = (tid & 15) * 8;

  for (int l = 0; l < 2; l++) {
    f32x4 acc[4][4];   // [mtj][ntj]
#pragma unroll
    for (int a = 0; a < 4; a++)
#pragma unroll
      for (int b = 0; b < 4; b++) acc[a][b] = f32x4{0.0f, 0.0f, 0.0f, 0.0f};
    const _Float16* wl = wf + l * (9 * 8 * 4 * 64 * 8);
    for (int r = 0; r < 9; r++) {
      __syncthreads();   // MFMA of r-1 done reading S (setup barrier covers r==0,l==0)
      // prefetch this wave's B-fragments AFTER the barrier -> overlaps aggregation
      f16x8 Bf[4][4];   // [ntj][kt]
      const _Float16* wr = wl + r * (8 * 4 * 64 * 8);
#pragma unroll
      for (int ntj = 0; ntj < 4; ntj++)
#pragma unroll
        for (int kt = 0; kt < 4; kt++)
          Bf[ntj][kt] = *((const f16x8*)(wr + (((ngrp * 4 + ntj) * 4 + kt) * 64 + lane) * 8));
      if (r < 8) {       // 4-chain CSR aggregation into S, packed f16 accumulate
        int rbase = r * P_;
#pragma unroll
        for (int half = 0; half < 2; half++) {
          int d0 = half * 128 + dsub;   // chains: d0, d0+32, d0+64, d0+96
          int o0[4], n[4];
#pragma unroll
          for (int c = 0; c < 4; c++) {
            int d = d0 + c * 32;
            if (d < P_) { int a0 = offsS[rbase + d]; int a1 = offsS[rbase + d + 1]; o0[c] = a0; n[c] = a1 - a0; }
            else { o0[c] = 0; n[c] = 0; }
          }
          int nm = n[0];
#pragma unroll
          for (int c = 1; c < 4; c++) nm = n[c] > nm ? n[c] : nm;
          f16x8 ac[4];
#pragma unroll
          for (int c = 0; c < 4; c++) ac[c] = f16x8{0, 0, 0, 0, 0, 0, 0, 0};
          for (int t = 0; t < nm; t++) {
#pragma unroll
            for (int c = 0; c < 4; c++) {
              if (t < n[c]) {
                int s = csrS[o0[c] + t];
                ac[c] += *((const f16x8*)&hbuf[s * HROW + c8]);   // v_pk_add_f16 x4
              }
            }
          }
#pragma unroll
          for (int c = 0; c < 4; c++) {
            int d = d0 + c * 32;
            if (d < P_) {
              float nf = n[c] > 0 ? 1.0f / (float)n[c] : 0.0f;
              _Float16 nh = (_Float16)nf;
              f16x8 o = ac[c] * nh;   // v_pk_mul_f16 x4
              *((f16x8*)&S[d * HROW + c8]) = o;
            }
          }
        }
      }
      __syncthreads();   // S ready, B arrived
      const _Float16* Ap = (r < 8) ? S : hbuf;   // root relation uses h
#pragma unroll
      for (int mtj = 0; mtj < 4; mtj++) {
        int mt = mgrp + mtj * 4;
        if (mt < 13) {
          int rowA = mt * 16 + lc; rowA = rowA < P_ ? rowA : P_ - 1;
#pragma unroll
          for (int kt = 0; kt < 4; kt++) {
            f16x8 a = *((const f16x8*)&Ap[rowA * HROW + kt * 32 + quad * 8]);
#pragma unroll
            for (int ntj = 0; ntj < 4; ntj++)
              acc[mtj][ntj] = __builtin_amdgcn_mfma_f32_16x16x32_f16(a, Bf[ntj][kt], acc[mtj][ntj], 0, 0, 0);
          }
        }
      }
    }
    __syncthreads();   // all MFMA readers of hbuf/S done
    if (l == 0) {
      // h' = relu(acc + b1) -> hbuf; C layout col=lane&15, row=quad*4+reg
#pragma unroll
      for (int mtj = 0; mtj < 4; mtj++) {
        int mt = mgrp + mtj * 4;
        if (mt < 13) {
#pragma unroll
          for (int ntj = 0; ntj < 4; ntj++) {
            int col = (ngrp * 4 + ntj) * 16 + lc;
            float bias = b1[col];
#pragma unroll
            for (int reg = 0; reg < 4; reg++) {
              int row = mt * 16 + quad * 4 + reg;
              float v = acc[mtj][ntj][reg] + bias;
              v = v > 0.0f ? v : 0.0f;
              if (row < P_) hbuf[row * HROW + col] = (_Float16)v;
            }
          }
        }
      }
      // next l-loop iteration starts with __syncthreads -> covers hbuf visibility
    } else {
      // score: dot(node_emb, msg) + dot(b2, msg); two ngrp partials via LDS
      float* scoreS = (float*)S;   // S free after barrier
#pragma unroll
      for (int mtj = 0; mtj < 4; mtj++) {
        int mt = mgrp + mtj * 4;
        if (mt < 13) {
#pragma unroll
          for (int reg = 0; reg < 4; reg++) {
            float p = 0.0f;
#pragma unroll
            for (int ntj = 0; ntj < 4; ntj++)
              p += acc[mtj][ntj][reg] * msgS[(ngrp * 4 + ntj) * 16 + lc];
            p += __shfl_xor(p, 8, 16);
            p += __shfl_xor(p, 4, 16);
            p += __shfl_xor(p, 2, 16);
            p += __shfl_xor(p, 1, 16);
            int row = mt * 16 + quad * 4 + reg;
            if (lc == 0 && row < P_) scoreS[ngrp * P_ + row] = p;
          }
        }
      }
      __syncthreads();
      for (int i = tid; i < P_; i += 512)
        out[g * P_ + i] = scoreS[i] + scoreS[P_ + i] + msgS[F_];
    }
  }
}

extern "C" void kernel_launch(void* const* d_in, const int* in_sizes, int n_in,
                              void* d_out, int out_size, void* d_ws, size_t ws_size,
                              hipStream_t stream) {
  const float* message = (const float*)d_in[0];
  const float* x       = (const float*)d_in[1];
  const int*   ei      = (const int*)d_in[2];
  const int*   et      = (const int*)d_in[3];
  const float* W1      = (const float*)d_in[6];
  const float* root1   = (const float*)d_in[7];
  const float* b1      = (const float*)d_in[8];
  const float* W2      = (const float*)d_in[9];
  const float* root2   = (const float*)d_in[10];
  const float* b2      = (const float*)d_in[11];
  const float* embed   = (const float*)d_in[12];
  const float* cw      = (const float*)d_in[13];
  const float* cb      = (const float*)d_in[14];
  const float* mw      = (const float*)d_in[15];
  const float* mb      = (const float*)d_in[16];

  _Float16* wfrag = (_Float16*)d_ws;   // 589,824 B
  float*    out   = (float*)d_out;

  hipLaunchKernelGGL(k_wstage, dim3(1152), dim3(256), 0, stream, W1, root1, W2, root2, wfrag);
  hipLaunchKernelGGL(k_main, dim3(G_), dim3(512), 0, stream, x, ei, et, wfrag, b1, b2,
                     message, embed, cw, cb, mw, mb, out);
}

// Round 5
// 189.208 us; speedup vs baseline: 21.4028x; 1.0948x over previous
//
#include <hip/hip_runtime.h>
#include <stdint.h>

#define G_   250
#define P_   200
#define EPG  3200
#define E_   800000
#define F_   128
#define R_   8
#define HROW 136   // f16 elems per row; 272 B stride, 16B-aligned rows, conflict-benign
#define NKEY (R_ * P_)   // 1600 (rel,dst) buckets

typedef _Float16 f16x8 __attribute__((ext_vector_type(8)));
typedef _Float16 f16x4 __attribute__((ext_vector_type(4)));
typedef float    f32x4 __attribute__((ext_vector_type(4)));

// ---------------- prepass: stage W1|root1, W2|root2 into B-fragment-native f16 layout --------
// flat = ((((l*9+r)*8 + nt)*4 + kt)*64 + lane)*8 + j ; value = W[r][k= kt*32+(lane>>4)*8+j][n= nt*16+(lane&15)]
__global__ __launch_bounds__(256) void k_wstage(const float* __restrict__ W1, const float* __restrict__ root1,
                                                const float* __restrict__ W2, const float* __restrict__ root2,
                                                _Float16* __restrict__ wf) {
  int t = blockIdx.x * 256 + threadIdx.x;
  if (t >= 2 * 9 * 8 * 4 * 64 * 8) return;
  int j = t & 7;
  int rest = t >> 3;
  int lane = rest & 63; rest >>= 6;
  int kt = rest & 3;    rest >>= 2;
  int nt = rest & 7;    rest >>= 3;
  int r = rest % 9;
  int l = rest / 9;
  int k = kt * 32 + (lane >> 4) * 8 + j;
  int n = nt * 16 + (lane & 15);
  const float* Wl = (l == 0) ? W1 : W2;
  const float* rl = (l == 0) ? root1 : root2;
  float v = (r < 8) ? Wl[(r * F_ + k) * F_ + n] : rl[k * F_ + n];
  wf[t] = (_Float16)v;
}

// ---------------- main: one workgroup = one graph; owner-computes, barrier-free K-loop --------
__global__ __launch_bounds__(512) void k_main(
    const float* __restrict__ x, const int* __restrict__ ei, const int* __restrict__ et,
    const _Float16* __restrict__ wf, const float* __restrict__ b1, const float* __restrict__ b2,
    const float* __restrict__ message, const float* __restrict__ embed,
    const float* __restrict__ cw, const float* __restrict__ cb,
    const float* __restrict__ mw, const float* __restrict__ mb,
    float* __restrict__ out) {
  __shared__ __attribute__((aligned(16))) _Float16 hbuf[P_ * HROW];   // 54400 B
  __shared__ unsigned short csrS[EPG];                                // 6400 B
  __shared__ int offsS[NKEY + 1];                                     // 6404 B
  __shared__ float msgS[F_ + 1];                                      // 516 B
  __shared__ float scoreS[2 * P_];                                    // 1600 B
  // setup-only scratch (dead after setup)
  __shared__ int cnt[NKEY];                                           // 6400 B
  __shared__ int cur[NKEY];                                           // 6400 B
  __shared__ int chunkTot[200];
  __shared__ int scanA[256];
  __shared__ int scanB[256];
  __shared__ int eRec[EPG];                                           // 12800 B
  __shared__ float comb[256];
  __shared__ float red[512];                                          // total ~100.8 KB

  int g = blockIdx.x, tid = threadIdx.x;
  int lane = tid & 63, wave = tid >> 6, quad = lane >> 4, lc = lane & 15;

  // ---- setup: stage x -> hbuf (f16) ----
  for (int i = tid; i < P_ * 32; i += 512) {
    int row = i >> 5, c4 = i & 31;
    const float4 v = ((const float4*)x)[(g * P_ + row) * 32 + c4];
    f16x4 pk = { (_Float16)v.x, (_Float16)v.y, (_Float16)v.z, (_Float16)v.w };
    *((f16x4*)&hbuf[row * HROW + c4 * 4]) = pk;
  }
  for (int i = tid; i < NKEY; i += 512) { cnt[i] = 0; cur[i] = 0; }
  if (tid < F_) {   // message combined features
    int tok = (int)message[g * 2];
    float cont = message[g * 2 + 1];
    comb[tid] = embed[tok * F_ + tid];
    float ce = cont * cw[tid] + cb[tid];
    comb[F_ + tid] = ce > 0.0f ? ce : 0.0f;
  }
  __syncthreads();
  // edge ingest: pack records into LDS + count buckets
  int base = g * EPG, nbase = g * P_;
  for (int e = tid; e < EPG; e += 512) {
    int s = ei[base + e] - nbase;
    int d = ei[E_ + base + e] - nbase;
    int r = et[base + e];
    eRec[e] = s | (d << 8) | (r << 16);
    atomicAdd(&cnt[r * P_ + d], 1);
  }
  __syncthreads();
  if (tid < 200) {   // per-chunk serial scan (8 buckets each)
    int s = 0;
    for (int i = 0; i < 8; i++) { int c = cnt[tid * 8 + i]; offsS[tid * 8 + i] = s; s += c; }
    chunkTot[tid] = s;
    scanA[tid] = s;
  }
  __syncthreads();
  {  // Hillis-Steele inclusive scan of chunkTot[200]
    int* src = scanA; int* dst = scanB;
    for (int st = 1; st < 256; st <<= 1) {
      if (tid < 200) dst[tid] = src[tid] + (tid >= st ? src[tid - st] : 0);
      __syncthreads();
      int* tmp = src; src = dst; dst = tmp;
    }
  }
  if (tid < 200) {
    int add = scanA[tid] - chunkTot[tid];   // exclusive chunk base
    for (int i = 0; i < 8; i++) offsS[tid * 8 + i] += add;
  }
  if (tid == 0) offsS[NKEY] = EPG;
  {   // message matmul partials: 4 segs x 128 cols
    int col = tid & 127, seg = tid >> 7;
    float acc = 0.0f;
#pragma unroll 8
    for (int k = seg * 64; k < seg * 64 + 64; k++) acc += comb[k] * mw[k * F_ + col];
    red[tid] = acc;
  }
  __syncthreads();
  // CSR scatter from LDS records
  for (int e = tid; e < EPG; e += 512) {
    int rec = eRec[e];
    int s = rec & 255, d = (rec >> 8) & 255, r = rec >> 16;
    int key = r * P_ + d;
    int pos = atomicAdd(&cur[key], 1);
    csrS[offsS[key] + pos] = (unsigned short)s;
  }
  if (tid < F_) {
    float a = mb[tid] + red[tid] + red[128 + tid] + red[256 + tid] + red[384 + tid];
    a = a > 0.0f ? a : 0.0f;
    msgS[tid] = a;
    comb[tid] = a * b2[tid];   // for db2 = dot(msg, b2)
  }
  __syncthreads();
  if (tid < 64) comb[tid] += comb[tid + 64];
  __syncthreads();
  if (tid < 32) comb[tid] += comb[tid + 32];
  __syncthreads();
  if (tid < 16) comb[tid] += comb[tid + 16];
  __syncthreads();
  if (tid == 0) {
    float s = 0.0f;
    for (int i = 0; i < 16; i++) s += comb[i];
    msgS[F_] = s;
  }
  __syncthreads();   // hbuf + csr + offs + msg all ready

  // ---- fused layers: owner-computes, no barriers inside the r-loop ----
  int mgrp = wave >> 1, ngrp = wave & 1;   // 4 x 2 wave grid
  int myD = lc;                             // row-within-tile handled by this lane
  int cq = quad * 8;                        // column base within 32-chunk

  for (int l = 0; l < 2; l++) {
    f32x4 acc[4][4];   // [mtj][ntj]
#pragma unroll
    for (int a = 0; a < 4; a++)
#pragma unroll
      for (int b = 0; b < 4; b++) acc[a][b] = f32x4{0.0f, 0.0f, 0.0f, 0.0f};
    const _Float16* wl = wf + l * (9 * 8 * 4 * 64 * 8);
    for (int r = 0; r < 9; r++) {
      // this wave's B-fragments from global (L2); in flight while gathering A
      f16x8 Bf[4][4];   // [ntj][kt]
      const _Float16* wr = wl + r * (8 * 4 * 64 * 8);
#pragma unroll
      for (int ntj = 0; ntj < 4; ntj++)
#pragma unroll
        for (int kt = 0; kt < 4; kt++)
          Bf[ntj][kt] = *((const f16x8*)(wr + (((ngrp * 4 + ntj) * 4 + kt) * 64 + lane) * 8));
#pragma unroll
      for (int mtj = 0; mtj < 4; mtj++) {
        int mt = mgrp + mtj * 4;
        if (mt < 13) {
          f16x8 a0, a1, a2, a3;
          if (r < 8) {
            // gather-aggregate this lane's row for relation r directly into A-regs
            int d = mt * 16 + myD;
            int o = 0, n = 0;
            if (d < P_) { int key = r * P_ + d; o = offsS[key]; n = offsS[key + 1] - o; }
            a0 = f16x8{0,0,0,0,0,0,0,0}; a1 = a0; a2 = a0; a3 = a0;
            int sNext = (n > 0) ? (int)csrS[o] : 0;
            for (int t = 0; t < n; t++) {
              int sc = sNext;
              if (t + 1 < n) sNext = (int)csrS[o + t + 1];
              const _Float16* hp = &hbuf[sc * HROW + cq];
              a0 += *((const f16x8*)(hp));
              a1 += *((const f16x8*)(hp + 32));
              a2 += *((const f16x8*)(hp + 64));
              a3 += *((const f16x8*)(hp + 96));
            }
            float nf = (n > 0) ? 1.0f / (float)n : 0.0f;
            _Float16 nh = (_Float16)nf;
            a0 *= nh; a1 *= nh; a2 *= nh; a3 *= nh;
          } else {
            // root relation: A = h rows directly
            int rowA = mt * 16 + myD; rowA = rowA < P_ ? rowA : P_ - 1;
            const _Float16* hp = &hbuf[rowA * HROW + cq];
            a0 = *((const f16x8*)(hp));
            a1 = *((const f16x8*)(hp + 32));
            a2 = *((const f16x8*)(hp + 64));
            a3 = *((const f16x8*)(hp + 96));
          }
#pragma unroll
          for (int ntj = 0; ntj < 4; ntj++) {
            acc[mtj][ntj] = __builtin_amdgcn_mfma_f32_16x16x32_f16(a0, Bf[ntj][0], acc[mtj][ntj], 0, 0, 0);
            acc[mtj][ntj] = __builtin_amdgcn_mfma_f32_16x16x32_f16(a1, Bf[ntj][1], acc[mtj][ntj], 0, 0, 0);
            acc[mtj][ntj] = __builtin_amdgcn_mfma_f32_16x16x32_f16(a2, Bf[ntj][2], acc[mtj][ntj], 0, 0, 0);
            acc[mtj][ntj] = __builtin_amdgcn_mfma_f32_16x16x32_f16(a3, Bf[ntj][3], acc[mtj][ntj], 0, 0, 0);
          }
        }
      }
    }
    __syncthreads();   // all waves done reading hbuf (r==8) before overwrite / scoring
    if (l == 0) {
      // h' = relu(acc + b1) -> hbuf; C layout col=lane&15, row=quad*4+reg
#pragma unroll
      for (int mtj = 0; mtj < 4; mtj++) {
        int mt = mgrp + mtj * 4;
        if (mt < 13) {
#pragma unroll
          for (int ntj = 0; ntj < 4; ntj++) {
            int col = (ngrp * 4 + ntj) * 16 + lc;
            float bias = b1[col];
#pragma unroll
            for (int reg = 0; reg < 4; reg++) {
              int row = mt * 16 + quad * 4 + reg;
              float v = acc[mtj][ntj][reg] + bias;
              v = v > 0.0f ? v : 0.0f;
              if (row < P_) hbuf[row * HROW + col] = (_Float16)v;
            }
          }
        }
      }
      __syncthreads();   // h' visible before layer-2 gathers
    } else {
      // score: dot(node_emb, msg) + dot(b2, msg); two ngrp partials via LDS
#pragma unroll
      for (int mtj = 0; mtj < 4; mtj++) {
        int mt = mgrp + mtj * 4;
        if (mt < 13) {
#pragma unroll
          for (int reg = 0; reg < 4; reg++) {
            float p = 0.0f;
#pragma unroll
            for (int ntj = 0; ntj < 4; ntj++)
              p += acc[mtj][ntj][reg] * msgS[(ngrp * 4 + ntj) * 16 + lc];
            p += __shfl_xor(p, 8, 16);
            p += __shfl_xor(p, 4, 16);
            p += __shfl_xor(p, 2, 16);
            p += __shfl_xor(p, 1, 16);
            int row = mt * 16 + quad * 4 + reg;
            if (lc == 0 && row < P_) scoreS[ngrp * P_ + row] = p;
          }
        }
      }
      __syncthreads();
      for (int i = tid; i < P_; i += 512)
        out[g * P_ + i] = scoreS[i] + scoreS[P_ + i] + msgS[F_];
    }
  }
}

extern "C" void kernel_launch(void* const* d_in, const int* in_sizes, int n_in,
                              void* d_out, int out_size, void* d_ws, size_t ws_size,
                              hipStream_t stream) {
  const float* message = (const float*)d_in[0];
  const float* x       = (const float*)d_in[1];
  const int*   ei      = (const int*)d_in[2];
  const int*   et      = (const int*)d_in[3];
  const float* W1      = (const float*)d_in[6];
  const float* root1   = (const float*)d_in[7];
  const float* b1      = (const float*)d_in[8];
  const float* W2      = (const float*)d_in[9];
  const float* root2   = (const float*)d_in[10];
  const float* b2      = (const float*)d_in[11];
  const float* embed   = (const float*)d_in[12];
  const float* cw      = (const float*)d_in[13];
  const float* cb      = (const float*)d_in[14];
  const float* mw      = (const float*)d_in[15];
  const float* mb      = (const float*)d_in[16];

  _Float16* wfrag = (_Float16*)d_ws;   // 589,824 B
  float*    out   = (float*)d_out;

  hipLaunchKernelGGL(k_wstage, dim3(1152), dim3(256), 0, stream, W1, root1, W2, root2, wfrag);
  hipLaunchKernelGGL(k_main, dim3(G_), dim3(512), 0, stream, x, ei, et, wfrag, b1, b2,
                     message, embed, cw, cb, mw, mb, out);
}